// Round 16
// baseline (94.133 us; speedup 1.0000x reference)
//
#include <hip/hip_runtime.h>

#define NN 100000
#define DD 384
#define CC 8
#define ROWS 64      // orig rows per block (4 waves x 16)

typedef unsigned int uint;
typedef _Float16 half8 __attribute__((ext_vector_type(8)));
typedef float floatx4 __attribute__((ext_vector_type(4)));

__device__ __forceinline__ constexpr int TIDX(int i, int j) { return i * (i + 1) / 2 + j; }

__device__ __forceinline__ uint pkh2(float a, float b) {
  return __builtin_bit_cast(uint, __builtin_amdgcn_cvt_pkrtz(a, b));
}

// B-fragment pre-pack (verified R8-R15). B[d][col]: col 0..35 = lower-tri of
// Sigmaw[d]+w w^T, 36..43 = wbar, 44..47 = 0.  mfma_f32_16x16x32_f16
// B-operand: lane holds 8 f16 at col = ct*16+(lane&15), k(j) = kt*32+(lane>>4)*8+j.
__global__ __launch_bounds__(64) void vbpca_prep(
    const float* __restrict__ wbar, const float* __restrict__ Sigmaw,
    uint4* __restrict__ bfrag) {
  const int l = threadIdx.x;
  const int kt = blockIdx.x;  // 0..11
  const int kgrp = l >> 4;
#pragma unroll
  for (int ct = 0; ct < 3; ++ct) {
    const int col = ct * 16 + (l & 15);
    int ii = 0;
#pragma unroll
    for (int t = 0; t < 7; ++t) {
      if ((ii + 1) * (ii + 2) / 2 <= col && ii < 7) ++ii;
    }
    const int jj = col - ii * (ii + 1) / 2;
    float v[8];
#pragma unroll
    for (int j = 0; j < 8; ++j) {
      const int d = kt * 32 + kgrp * 8 + j;
      float val;
      if (col < 36) {
        val = Sigmaw[(size_t)d * 64 + ii * 8 + jj] + wbar[d * 8 + ii] * wbar[d * 8 + jj];
      } else if (col < 44) {
        val = wbar[d * 8 + (col - 36)];
      } else {
        val = 0.f;
      }
      v[j] = val;
    }
    uint4 u;
    u.x = pkh2(v[0], v[1]); u.y = pkh2(v[2], v[3]);
    u.z = pkh2(v[4], v[5]); u.w = pkh2(v[6], v[7]);
    bfrag[(kt * 3 + ct) * 64 + l] = u;
  }
}

// global_load_lds staged design: wave-private double-buffered LDS staging of
// raw Y/O (async DMA, no VGPR dest -> compiler cannot sink; no barriers in
// main loop -> no forced vmcnt(0)). Straight-line 8-step pipeline; step =
// 8 rows x 96 ch; source-side XOR swizzle c4^=(r&7) makes frag reads
// bank-conflict-free. Fragments built in regs (R15 branchless formula).
__global__ __launch_bounds__(256, 3) void vbpca_main(
    const float* __restrict__ Y, const int* __restrict__ O,
    const uint4* __restrict__ bfrag, const float* __restrict__ mbar,
    const float* __restrict__ vyp, float* __restrict__ out) {
  __shared__ uint smem[12672];  // 50688 B -> 3 blocks/CU
  uint* tile = smem;                      // [4 waves][2 bufs][1536] uints
  float* mbar_l = (float*)(smem + 12288); // [384]
  float* scat_l = (float*)smem;           // [128][49] overlay on tile
  float* sigst = (float*)smem;            // [64][65] overlay
  float* xbst = (float*)smem + 4160;      // [64][9]

  const int tid = threadIdx.x;
  const int wu = __builtin_amdgcn_readfirstlane((int)(tid >> 6));
  const int l = tid & 63;

  for (int i = tid; i < DD; i += 256) mbar_l[i] = mbar[i];
  __syncthreads();  // mbar ready (only barrier before epilogue)

  uint* wbuf = tile + wu * 3072;
  const int rt0 = blockIdx.x * ROWS + wu * 16;  // mtile0 rows rt0..rt0+7; mtile1 +8
  const float tsel = (float)(l & 1);
  const float osel = 1.f - tsel;

#define GLOAD16(GSRC, LDST)                                                  \
  __builtin_amdgcn_global_load_lds(                                          \
      (const __attribute__((address_space(1))) void*)(GSRC),                 \
      (__attribute__((address_space(3))) void*)(LDST), 16, 0, 0)

  // Issue step (M,S) into BUF: 3 Y + 3 O global_load_lds_dwordx4.
  // Physical slot p = i*64+l; r = p/24; c4 = (p%24) ^ (r&7)  (source-swizzled).
#define ISSUE(M, S, BUF)                                                     \
  {                                                                          \
    _Pragma("unroll") for (int i = 0; i < 3; ++i) {                          \
      const int p = i * 64 + l;                                              \
      const int r = p / 24;                                                  \
      const int c4 = (p - r * 24) ^ (r & 7);                                 \
      int row = rt0 + (M)*8 + r;                                             \
      row = row < NN ? row : NN - 1;                                         \
      const size_t goff = (size_t)row * 96 + (S)*24 + c4;                    \
      GLOAD16(reinterpret_cast<const float4*>(Y) + goff,                     \
              wbuf + (BUF)*1536 + i * 256 + l * 4);                          \
      GLOAD16(reinterpret_cast<const int4*>(O) + goff,                       \
              wbuf + (BUF)*1536 + 768 + i * 256 + l * 4);                    \
    }                                                                        \
  }

  floatx4 accA[3], accB[3];
#pragma unroll
  for (int j = 0; j < 3; ++j) {
    accA[j] = (floatx4){0.f, 0.f, 0.f, 0.f};
    accB[j] = (floatx4){0.f, 0.f, 0.f, 0.f};
  }
  uint4 bf0, bf1, bf2;

  // Build A-frag for kt (global 0..11) = step S, sub J from BUF (regs only).
#define FRAG(S, J, BUF, AV)                                                  \
  half8 AV;                                                                  \
  {                                                                          \
    const int ktg = (S)*3 + (J);                                             \
    const int r = (l & 15) >> 1;                                             \
    const int c4a = (J)*8 + (l >> 4) * 2;                                    \
    const uint* bb = wbuf + (BUF)*1536;                                      \
    const float4 ylo = *reinterpret_cast<const float4*>(                     \
        bb + (r * 24 + ((c4a) ^ (r & 7))) * 4);                              \
    const float4 yhi = *reinterpret_cast<const float4*>(                     \
        bb + (r * 24 + ((c4a + 1) ^ (r & 7))) * 4);                          \
    const int4 olo = *reinterpret_cast<const int4*>(                         \
        bb + 768 + (r * 24 + ((c4a) ^ (r & 7))) * 4);                        \
    const int4 ohi = *reinterpret_cast<const int4*>(                         \
        bb + 768 + (r * 24 + ((c4a + 1) ^ (r & 7))) * 4);                    \
    const float4 mlo =                                                       \
        *reinterpret_cast<const float4*>(mbar_l + ktg * 32 + (l >> 4) * 8);  \
    const float4 mhi = *reinterpret_cast<const float4*>(                     \
        mbar_l + ktg * 32 + (l >> 4) * 8 + 4);                               \
    const float v0 = (float)olo.x * fmaf(tsel, ylo.x - mlo.x, osel);         \
    const float v1 = (float)olo.y * fmaf(tsel, ylo.y - mlo.y, osel);         \
    const float v2 = (float)olo.z * fmaf(tsel, ylo.z - mlo.z, osel);         \
    const float v3 = (float)olo.w * fmaf(tsel, ylo.w - mlo.w, osel);         \
    const float v4 = (float)ohi.x * fmaf(tsel, yhi.x - mhi.x, osel);         \
    const float v5 = (float)ohi.y * fmaf(tsel, yhi.y - mhi.y, osel);         \
    const float v6 = (float)ohi.z * fmaf(tsel, yhi.z - mhi.z, osel);         \
    const float v7 = (float)ohi.w * fmaf(tsel, yhi.w - mhi.w, osel);         \
    uint4 fu;                                                                \
    fu.x = pkh2(v0, v1); fu.y = pkh2(v2, v3);                                \
    fu.z = pkh2(v4, v5); fu.w = pkh2(v6, v7);                                \
    AV = __builtin_bit_cast(half8, fu);                                      \
  }

#define KT_BODY(S, J, BUF, ACC)                                              \
  {                                                                          \
    FRAG(S, J, BUF, av);                                                     \
    const int ktn = (S)*3 + (J) + 1;                                         \
    uint4 nb0, nb1, nb2;                                                     \
    if (ktn < 12) {                                                          \
      nb0 = bfrag[(ktn * 3 + 0) * 64 + l];                                   \
      nb1 = bfrag[(ktn * 3 + 1) * 64 + l];                                   \
      nb2 = bfrag[(ktn * 3 + 2) * 64 + l];                                   \
    }                                                                        \
    ACC[0] = __builtin_amdgcn_mfma_f32_16x16x32_f16(                         \
        av, __builtin_bit_cast(half8, bf0), ACC[0], 0, 0, 0);                \
    ACC[1] = __builtin_amdgcn_mfma_f32_16x16x32_f16(                         \
        av, __builtin_bit_cast(half8, bf1), ACC[1], 0, 0, 0);                \
    ACC[2] = __builtin_amdgcn_mfma_f32_16x16x32_f16(                         \
        av, __builtin_bit_cast(half8, bf2), ACC[2], 0, 0, 0);                \
    bf0 = nb0; bf1 = nb1; bf2 = nb2;                                         \
  }

#define BPRELOAD()                                                           \
  bf0 = bfrag[0 * 64 + l];                                                   \
  bf1 = bfrag[1 * 64 + l];                                                   \
  bf2 = bfrag[2 * 64 + l];

#define STEP(S, BUF, ACC)                                                    \
  KT_BODY(S, 0, BUF, ACC);                                                   \
  KT_BODY(S, 1, BUF, ACC);                                                   \
  KT_BODY(S, 2, BUF, ACC);

  // ---- straight-line 8-step pipeline, 2 buffers, no barriers ----
  ISSUE(0, 0, 0);
  ISSUE(0, 1, 1);
  BPRELOAD();
  STEP(0, 0, accA);  ISSUE(0, 2, 0);
  STEP(1, 1, accA);  ISSUE(0, 3, 1);
  STEP(2, 0, accA);  ISSUE(1, 0, 0);
  STEP(3, 1, accA);  ISSUE(1, 1, 1);
  BPRELOAD();
  STEP(0, 0, accB);  ISSUE(1, 2, 0);
  STEP(1, 1, accB);  ISSUE(1, 3, 1);
  STEP(2, 0, accB);
  STEP(3, 1, accB);

  // ---- epilogue (verified R9-R15) ----
  __syncthreads();

#pragma unroll
  for (int ct = 0; ct < 3; ++ct) {
#pragma unroll
    for (int reg = 0; reg < 4; ++reg) {
      const int m = (l >> 4) * 4 + reg;
      scat_l[(wu * 32 + m) * 49 + ct * 16 + (l & 15)] = accA[ct][reg];
      scat_l[(wu * 32 + 16 + m) * 49 + ct * 16 + (l & 15)] = accB[ct][reg];
    }
  }
  __syncthreads();

  float a[36], pr[CC];
  if (tid < 64) {
#pragma unroll
    for (int k = 0; k < 36; ++k) a[k] = scat_l[(2 * tid) * 49 + k];
#pragma unroll
    for (int j = 0; j < CC; ++j) pr[j] = scat_l[(2 * tid + 1) * 49 + 36 + j];
  }
  __syncthreads();  // scat reads complete before sigst overwrite

  if (tid < 64) {
    const int row = tid;
    const float vy = *vyp;

    float L[36];
#pragma unroll
    for (int j = 0; j < CC; ++j) {
      float s = a[TIDX(j, j)] + vy;
#pragma unroll
      for (int k = 0; k < CC; ++k) {
        if (k < j) s -= L[TIDX(j, k)] * L[TIDX(j, k)];
      }
      const float dj = sqrtf(s);
      L[TIDX(j, j)] = dj;
      const float invdj = 1.0f / dj;
#pragma unroll
      for (int i = j + 1; i < CC; ++i) {
        float tt = a[TIDX(i, j)];
#pragma unroll
        for (int k = 0; k < CC; ++k) {
          if (k < j) tt -= L[TIDX(i, k)] * L[TIDX(j, k)];
        }
        L[TIDX(i, j)] = tt * invdj;
      }
    }

    float invd[CC];
#pragma unroll
    for (int i = 0; i < CC; ++i) invd[i] = 1.0f / L[TIDX(i, i)];
    float Li[36];
#pragma unroll
    for (int j = 0; j < CC; ++j) {
      Li[TIDX(j, j)] = invd[j];
#pragma unroll
      for (int i = j + 1; i < CC; ++i) {
        float s = 0.f;
#pragma unroll
        for (int k = 0; k < CC; ++k) {
          if (k >= j && k < i) s += L[TIDX(i, k)] * Li[TIDX(k, j)];
        }
        Li[TIDX(i, j)] = -s * invd[i];
      }
    }

    float sig[36];
#pragma unroll
    for (int i = 0; i < CC; ++i) {
#pragma unroll
      for (int j = 0; j <= i; ++j) {
        float s = 0.f;
#pragma unroll
        for (int k = 0; k < CC; ++k) {
          if (k >= i) s += Li[TIDX(k, i)] * Li[TIDX(k, j)];
        }
        sig[TIDX(i, j)] = vy * s;
      }
    }

    float uvec[CC];
#pragma unroll
    for (int i = 0; i < CC; ++i) {
      float s = 0.f;
#pragma unroll
      for (int j = 0; j < CC; ++j) {
        if (j <= i) s += Li[TIDX(i, j)] * pr[j];
      }
      uvec[i] = s;
    }
#pragma unroll
    for (int ll = 0; ll < CC; ++ll) {
      float s = 0.f;
#pragma unroll
      for (int i = 0; i < CC; ++i) {
        if (i >= ll) s += Li[TIDX(i, ll)] * uvec[i];
      }
      xbst[row * 9 + ll] = s;
    }
#pragma unroll
    for (int i = 0; i < CC; ++i) {
#pragma unroll
      for (int j = 0; j < CC; ++j) {
        sigst[row * 65 + i * 8 + j] = (j <= i) ? sig[TIDX(i, j)] : sig[TIDX(j, i)];
      }
    }
  }
  __syncthreads();

  // ---- coalesced copy-out ----
  const int valid = (NN - blockIdx.x * ROWS < ROWS) ? (NN - blockIdx.x * ROWS) : ROWS;
  float* __restrict__ sig_out = out + (size_t)NN * CC + (size_t)blockIdx.x * ROWS * 64;
  for (int f = tid; f < valid * 64; f += 256) {
    sig_out[f] = sigst[(f >> 6) * 65 + (f & 63)];
  }
  float* __restrict__ xb_out = out + (size_t)blockIdx.x * ROWS * CC;
  for (int f = tid; f < valid * 8; f += 256) {
    xb_out[f] = xbst[(f >> 3) * 9 + (f & 7)];
  }
}

extern "C" void kernel_launch(void* const* d_in, const int* in_sizes, int n_in,
                              void* d_out, int out_size, void* d_ws, size_t ws_size,
                              hipStream_t stream) {
  const float* Y = (const float*)d_in[0];
  const int* O = (const int*)d_in[1];
  const float* mbar = (const float*)d_in[2];
  const float* wbar = (const float*)d_in[3];
  const float* Sigmaw = (const float*)d_in[4];
  const float* vyp = (const float*)d_in[5];
  float* out = (float*)d_out;
  uint4* bfrag = (uint4*)d_ws;  // 12*3*64*16 = 36864 bytes

  vbpca_prep<<<12, 64, 0, stream>>>(wbar, Sigmaw, bfrag);
  vbpca_main<<<(NN + ROWS - 1) / ROWS, 256, 0, stream>>>(Y, O, bfrag, mbar, vyp, out);
}